// Round 7
// baseline (2487.890 us; speedup 1.0000x reference)
//
#include <hip/hip_runtime.h>
#include <hip/hip_bf16.h>
#include <stdint.h>

// ---------------------------------------------------------------------------
// bf16 pack/unpack via pure bit ops (v_lshlrev / v_and / v_add) — no unions,
// no vector builtins (those demoted arrays to scratch in rounds 4-5).
// ---------------------------------------------------------------------------
__device__ __forceinline__ float blo(uint32_t u) { return __uint_as_float(u << 16); }
__device__ __forceinline__ float bhi(uint32_t u) { return __uint_as_float(u & 0xFFFF0000u); }
__device__ __forceinline__ uint32_t bpack(float lo, float hi) {
    uint32_t ulo = __float_as_uint(lo), uhi = __float_as_uint(hi);
    return ((ulo + 0x8000u) >> 16) | ((uhi + 0x8000u) & 0xFFFF0000u);  // RN-ish
}

// ---------------------------------------------------------------------------
// DPP helpers: reductions within each 16-lane row (VALU pipe, no LDS traffic)
// ---------------------------------------------------------------------------
template <int CTRL>
__device__ __forceinline__ float dppmov(float v) {
    return __int_as_float(__builtin_amdgcn_update_dpp(
        0, __float_as_int(v), CTRL, 0xF, 0xF, true));
}
__device__ __forceinline__ float grp_sum16(float v) {
    v += dppmov<0xB1>(v);   // quad_perm xor1
    v += dppmov<0x4E>(v);   // quad_perm xor2
    v += dppmov<0x124>(v);  // row_ror:4
    v += dppmov<0x128>(v);  // row_ror:8
    return v;
}
__device__ __forceinline__ float grp_max16(float v) {
    v = fmaxf(v, dppmov<0xB1>(v));
    v = fmaxf(v, dppmov<0x4E>(v));
    v = fmaxf(v, dppmov<0x124>(v));
    v = fmaxf(v, dppmov<0x128>(v));
    return v;
}

// ---------------------------------------------------------------------------
// Generic fp32 tiled GEMM (unchanged)
// ---------------------------------------------------------------------------
#define TM 64
#define TN 64
#define TK 16

__global__ __launch_bounds__(256) void gemm_tiled(
    const float* __restrict__ A, int lda,
    const float* __restrict__ B, int ldb,
    float* __restrict__ C, int ldc,
    int M, int N, int kc, const float* __restrict__ bias)
{
    __shared__ float As[TK][TM + 4];
    __shared__ float Bs[TK][TN + 4];
    const int tid = threadIdx.x;
    const int bm = blockIdx.y * TM;
    const int bn = blockIdx.x * TN;
    const int k0 = blockIdx.z * kc;
    C += (size_t)blockIdx.z * M * N;

    const int tx = tid & 15;
    const int ty = tid >> 4;

    float acc[4][4];
#pragma unroll
    for (int i = 0; i < 4; ++i)
#pragma unroll
        for (int j = 0; j < 4; ++j)
            acc[i][j] = bias ? bias[bn + tx * 4 + j] : 0.0f;

    const int ar = tid >> 2;
    const int ac = (tid & 3) * 4;
    const int br = tid >> 4;
    const int bc = (tid & 15) * 4;

    for (int kt = k0; kt < k0 + kc; kt += TK) {
        float4 a = *(const float4*)&A[(size_t)(bm + ar) * lda + kt + ac];
        float4 b = *(const float4*)&B[(size_t)(kt + br) * ldb + bn + bc];
        As[ac + 0][ar] = a.x; As[ac + 1][ar] = a.y;
        As[ac + 2][ar] = a.z; As[ac + 3][ar] = a.w;
        *(float4*)&Bs[br][bc] = b;
        __syncthreads();
#pragma unroll
        for (int kk = 0; kk < TK; ++kk) {
            float4 a4 = *(const float4*)&As[kk][ty * 4];
            float4 b4 = *(const float4*)&Bs[kk][tx * 4];
            float av[4] = {a4.x, a4.y, a4.z, a4.w};
            float bv[4] = {b4.x, b4.y, b4.z, b4.w};
#pragma unroll
            for (int i = 0; i < 4; ++i)
#pragma unroll
                for (int j = 0; j < 4; ++j)
                    acc[i][j] = fmaf(av[i], bv[j], acc[i][j]);
        }
        __syncthreads();
    }
#pragma unroll
    for (int i = 0; i < 4; ++i) {
        float4 o = make_float4(acc[i][0], acc[i][1], acc[i][2], acc[i][3]);
        *(float4*)&C[(size_t)(bm + ty * 4 + i) * ldc + bn + tx * 4] = o;
    }
}

// ---------------------------------------------------------------------------
// Fused per-half-token kernel, round 7: 2 rows per 16-lane group (each K/V
// LDS read feeds 2 rows' fmas; 2 independent solve chains for ILP) + K/V
// stored bf16-packed in LDS (half the LDS bytes; unpack = 1 shift/and per
// element). q pre-scaled by (alpha-1)/sqrt(512) at staging. Solver is the
// round-6-validated mean-seeded exact active-set solve (4 sweeps).
// LDS 24 KB; all per-element loops fully unrolled (static indices only).
// ---------------------------------------------------------------------------
#define NSOLVE 4
#define NBISECT 3
#define NNEWTON 6

__global__ __launch_bounds__(256, 3) void attn_entmax(
    const float* qg, const float* kg, const float* vg,
    float* resg, const float* __restrict__ alpha_p)
{
    __shared__ uint32_t ks16[8 * 256];   // [h][j2]: (k[h,2j2], k[h,2j2+1]) bf16
    __shared__ uint32_t vs16[8 * 256];   // [h][j2]: (v[h,2j2], v[h,2j2+1]) bf16
    __shared__ float    qs[8 * 256];     // pre-scaled f32 q, this block's rows

    const int t = blockIdx.x >> 1;
    const int base = (blockIdx.x & 1) << 8;    // row half: 0 or 256
    const int tid = threadIdx.x;

    const float alpha = alpha_p[0];
    const float expo = 1.0f / (alpha - 1.0f);      // = 2 for alpha=1.5 (exact)
    const bool fast = (expo == 2.0f);
    const float scl = (alpha - 1.0f) * 0.04419417382415922f;  // (a-1)/sqrt(512)
    const float hispan = powf(1.0f / 512.0f, alpha - 1.0f);   // m - tau_hi

    {   // ---- stage K,V (bf16-packed) and q (f32, pre-scaled)
        const float4* k4 = (const float4*)(kg + (size_t)t * 4096);
        const float4* v4 = (const float4*)(vg + (size_t)t * 4096);
#pragma unroll
        for (int a0 = 0; a0 < 4; ++a0) {
            int idx = tid + 256 * a0;          // 0..1023: h = idx>>7, j4 = idx&127
            int h = idx >> 7, j4 = idx & 127;
            float4 gk = k4[idx];
            float4 gv = v4[idx];
            *(uint2*)&ks16[h * 256 + 2 * j4] =
                make_uint2(bpack(gk.x, gk.y), bpack(gk.z, gk.w));
            *(uint2*)&vs16[h * 256 + 2 * j4] =
                make_uint2(bpack(gv.x, gv.y), bpack(gv.z, gv.w));
        }
        const float4* q4 = (const float4*)(qg + (size_t)t * 4096);
#pragma unroll
        for (int u = 0; u < 2; ++u) {
            int idx = tid + 256 * u;           // = h*64 + i4
            float4 g = q4[(idx >> 6) * 128 + (base >> 2) + (idx & 63)];
            g.x *= scl; g.y *= scl; g.z *= scl; g.w *= scl;
            ((float4*)qs)[idx] = g;
        }
    }
    __syncthreads();

    const int lane = tid & 63;
    const int w = tid >> 6;        // wave 0..3
    const int sub = lane >> 4;     // 16-lane group 0..3
    const int lx = lane & 15;

    for (int it = 0; it < 8; ++it) {
        const int il0 = it * 32 + w * 4 + sub;   // rows: this group's pair
        const int il1 = il0 + 16;

        float qv0[8], qv1[8];
#pragma unroll
        for (int h = 0; h < 8; ++h) {
            qv0[h] = qs[h * 256 + il0];
            qv1[h] = qs[h * 256 + il1];
        }

        // ---- scores for BOTH rows; lane's 32 cols: j = 8*lx + 128*u + e
        float x0[32], x1[32];
        float m0 = -1e30f, m1 = -1e30f, sa0 = 0.0f, sa1 = 0.0f;
#pragma unroll
        for (int u = 0; u < 4; ++u) {
            float a0=0,a1=0,a2=0,a3=0,a4=0,a5=0,a6=0,a7=0;
            float b0=0,b1=0,b2=0,b3=0,b4=0,b5=0,b6=0,b7=0;
#pragma unroll
            for (int h = 0; h < 8; ++h) {
                uint4 kk = *(const uint4*)&ks16[h * 256 + lx * 4 + 64 * u];
                float q0 = qv0[h], q1 = qv1[h];
                float e0 = blo(kk.x), e1 = bhi(kk.x);
                float e2 = blo(kk.y), e3 = bhi(kk.y);
                float e4 = blo(kk.z), e5 = bhi(kk.z);
                float e6 = blo(kk.w), e7 = bhi(kk.w);
                a0 = fmaf(q0, e0, a0); a1 = fmaf(q0, e1, a1);
                a2 = fmaf(q0, e2, a2); a3 = fmaf(q0, e3, a3);
                a4 = fmaf(q0, e4, a4); a5 = fmaf(q0, e5, a5);
                a6 = fmaf(q0, e6, a6); a7 = fmaf(q0, e7, a7);
                b0 = fmaf(q1, e0, b0); b1 = fmaf(q1, e1, b1);
                b2 = fmaf(q1, e2, b2); b3 = fmaf(q1, e3, b3);
                b4 = fmaf(q1, e4, b4); b5 = fmaf(q1, e5, b5);
                b6 = fmaf(q1, e6, b6); b7 = fmaf(q1, e7, b7);
            }
            x0[8*u+0]=a0; x0[8*u+1]=a1; x0[8*u+2]=a2; x0[8*u+3]=a3;
            x0[8*u+4]=a4; x0[8*u+5]=a5; x0[8*u+6]=a6; x0[8*u+7]=a7;
            x1[8*u+0]=b0; x1[8*u+1]=b1; x1[8*u+2]=b2; x1[8*u+3]=b3;
            x1[8*u+4]=b4; x1[8*u+5]=b5; x1[8*u+6]=b6; x1[8*u+7]=b7;
            m0 = fmaxf(m0, fmaxf(fmaxf(fmaxf(a0,a1),fmaxf(a2,a3)),
                                 fmaxf(fmaxf(a4,a5),fmaxf(a6,a7))));
            m1 = fmaxf(m1, fmaxf(fmaxf(fmaxf(b0,b1),fmaxf(b2,b3)),
                                 fmaxf(fmaxf(b4,b5),fmaxf(b6,b7))));
            sa0 += ((a0+a1)+(a2+a3)) + ((a4+a5)+(a6+a7));
            sa1 += ((b0+b1)+(b2+b3)) + ((b4+b5)+(b6+b7));
        }
        m0 = grp_max16(m0);
        m1 = grp_max16(m1);
        const float tlo0 = m0 - 1.0f, thi0 = m0 - hispan;
        const float tlo1 = m1 - 1.0f, thi1 = m1 - hispan;

        float tau0, tau1;
        if (fast) {
            sa0 = grp_sum16(sa0);
            sa1 = grp_sum16(sa1);
            tau0 = fminf(fmaxf(sa0 * (1.0f / 512.0f), tlo0), thi0);
            tau1 = fminf(fmaxf(sa1 * (1.0f / 512.0f), tlo1), thi1);
#pragma unroll
            for (int itr = 0; itr < NSOLVE; ++itr) {
                float s10=0, s20=0, n0=0, s11=0, s21=0, n1=0;
#pragma unroll
                for (int j = 0; j < 32; ++j) {
                    float r0 = x0[j] - tau0, rp0 = fmaxf(r0, 0.0f);
                    s10 += rp0; s20 = fmaf(rp0, rp0, s20);
                    n0 += (r0 > 0.0f) ? 1.0f : 0.0f;
                    float r1 = x1[j] - tau1, rp1 = fmaxf(r1, 0.0f);
                    s11 += rp1; s21 = fmaf(rp1, rp1, s21);
                    n1 += (r1 > 0.0f) ? 1.0f : 0.0f;
                }
                s10 = grp_sum16(s10); s20 = grp_sum16(s20); n0 = grp_sum16(n0);
                s11 = grp_sum16(s11); s21 = grp_sum16(s21); n1 = grp_sum16(n1);
                float d0 = fmaxf(fmaf(s10, s10, -n0 * (s20 - 1.0f)), 0.0f);
                float d1 = fmaxf(fmaf(s11, s11, -n1 * (s21 - 1.0f)), 0.0f);
                tau0 += (s10 - sqrtf(d0)) / fmaxf(n0, 1.0f);
                tau1 += (s11 - sqrtf(d1)) / fmaxf(n1, 1.0f);
                tau0 = fminf(fmaxf(tau0, tlo0), thi0);
                tau1 = fminf(fmaxf(tau1, tlo1), thi1);
            }
        } else {
            // generic alpha: bisect + Newton (powf path), both rows
            tau0 = tlo0; tau1 = tlo1;
            float dm = 1.0f - hispan;
#pragma unroll
            for (int bi = 0; bi < NBISECT; ++bi) {
                dm *= 0.5f;
                float tm0 = tau0 + dm, tm1 = tau1 + dm;
                float f0 = 0.0f, f1 = 0.0f;
#pragma unroll
                for (int j = 0; j < 32; ++j) {
                    f0 += __powf(fmaxf(x0[j] - tm0, 0.0f), expo);
                    f1 += __powf(fmaxf(x1[j] - tm1, 0.0f), expo);
                }
                f0 = grp_sum16(f0);
                f1 = grp_sum16(f1);
                if (f0 >= 1.0f) tau0 = tm0;
                if (f1 >= 1.0f) tau1 = tm1;
            }
#pragma unroll
            for (int ni = 0; ni < NNEWTON; ++ni) {
                float f0=0, g0=0, f1=0, g1=0;
#pragma unroll
                for (int j = 0; j < 32; ++j) {
                    float r0 = fmaxf(x0[j] - tau0, 0.0f);
                    float rp0 = __powf(r0, expo - 1.0f);
                    g0 += rp0; f0 += rp0 * r0;
                    float r1 = fmaxf(x1[j] - tau1, 0.0f);
                    float rp1 = __powf(r1, expo - 1.0f);
                    g1 += rp1; f1 += rp1 * r1;
                }
                f0 = grp_sum16(f0); g0 = grp_sum16(g0);
                f1 = grp_sum16(f1); g1 = grp_sum16(g1);
                tau0 += (f0 - 1.0f) / fmaxf(expo * g0, 1e-30f);
                tau1 += (f1 - 1.0f) / fmaxf(expo * g1, 1e-30f);
                tau0 = fminf(fmaxf(tau0, tlo0), thi0);
                tau1 = fminf(fmaxf(tau1, tlo1), thi1);
            }
        }

        // ---- final p (unnormalized) back into x; S for normalization
        float S0 = 0.0f, S1 = 0.0f;
        if (fast) {
#pragma unroll
            for (int j = 0; j < 32; ++j) {
                float r0 = fmaxf(x0[j] - tau0, 0.0f); x0[j] = r0 * r0; S0 += x0[j];
                float r1 = fmaxf(x1[j] - tau1, 0.0f); x1[j] = r1 * r1; S1 += x1[j];
            }
        } else {
#pragma unroll
            for (int j = 0; j < 32; ++j) {
                float p0 = __powf(fmaxf(x0[j] - tau0, 0.0f), expo);
                float p1 = __powf(fmaxf(x1[j] - tau1, 0.0f), expo);
                x0[j] = p0; S0 += p0;
                x1[j] = p1; S1 += p1;
            }
        }
        S0 = grp_sum16(S0);
        S1 = grp_sum16(S1);
        const float iS0 = 1.0f / S0, iS1 = 1.0f / S1;

        // ---- res[h,i] = invS * sum_j p[j] v[h,j]; V reads shared by 2 rows
#pragma unroll
        for (int h = 0; h < 8; ++h) {
            float a0 = 0.0f, a1 = 0.0f;
#pragma unroll
            for (int u = 0; u < 4; ++u) {
                uint4 vv = *(const uint4*)&vs16[h * 256 + lx * 4 + 64 * u];
                float e0 = blo(vv.x), e1 = bhi(vv.x);
                float e2 = blo(vv.y), e3 = bhi(vv.y);
                float e4 = blo(vv.z), e5 = bhi(vv.z);
                float e6 = blo(vv.w), e7 = bhi(vv.w);
                a0 = fmaf(x0[8*u+0], e0, a0); a0 = fmaf(x0[8*u+1], e1, a0);
                a0 = fmaf(x0[8*u+2], e2, a0); a0 = fmaf(x0[8*u+3], e3, a0);
                a0 = fmaf(x0[8*u+4], e4, a0); a0 = fmaf(x0[8*u+5], e5, a0);
                a0 = fmaf(x0[8*u+6], e6, a0); a0 = fmaf(x0[8*u+7], e7, a0);
                a1 = fmaf(x1[8*u+0], e0, a1); a1 = fmaf(x1[8*u+1], e1, a1);
                a1 = fmaf(x1[8*u+2], e2, a1); a1 = fmaf(x1[8*u+3], e3, a1);
                a1 = fmaf(x1[8*u+4], e4, a1); a1 = fmaf(x1[8*u+5], e5, a1);
                a1 = fmaf(x1[8*u+6], e6, a1); a1 = fmaf(x1[8*u+7], e7, a1);
            }
            a0 = grp_sum16(a0) * iS0;
            a1 = grp_sum16(a1) * iS1;
            if (lx == h) {
                resg[(size_t)t * 4096 + h * 512 + base + il0] = a0;
                resg[(size_t)t * 4096 + h * 512 + base + il1] = a1;
            }
        }
    }
}

// ---------------------------------------------------------------------------
__global__ __launch_bounds__(256) void reduce_bias(
    const float* __restrict__ part, const float* __restrict__ bu,
    float* __restrict__ out, int MN, int S)
{
    int i = blockIdx.x * 256 + threadIdx.x;
    if (i >= MN) return;
    float a = bu[i & 511];
#pragma unroll
    for (int s = 0; s < 8; ++s) a += part[(size_t)s * MN + i];
    out[i] = a;
}

// ---------------------------------------------------------------------------
extern "C" void kernel_launch(void* const* d_in, const int* in_sizes, int n_in,
                              void* d_out, int out_size, void* d_ws, size_t ws_size,
                              hipStream_t stream)
{
    const float* x  = (const float*)d_in[0];
    const float* Wq = (const float*)d_in[1];
    const float* bq = (const float*)d_in[2];
    const float* Wk = (const float*)d_in[3];
    const float* bk = (const float*)d_in[4];
    const float* Wv = (const float*)d_in[5];
    const float* bv = (const float*)d_in[6];
    const float* Wu = (const float*)d_in[7];
    const float* bu = (const float*)d_in[8];
    const float* al = (const float*)d_in[9];
    float* out = (float*)d_out;
    float* ws = (float*)d_ws;

    // ws layout (floats): q[2M] | k[2M] | v[2M]
    // res aliases q (each attn block reads only its own q slice, then writes
    // the same slice); split-K partials alias k (k dead after attn_entmax).
    float* q = ws;
    float* k = ws + 2097152;
    float* v = ws + 2 * 2097152;
    float* res = q;
    float* part = k;

    dim3 blk(256);

    dim3 g1(4096 / TN, 512 / TM, 1);
    gemm_tiled<<<g1, blk, 0, stream>>>(x, 512, Wq, 4096, q, 4096, 512, 4096, 512, bq);
    gemm_tiled<<<g1, blk, 0, stream>>>(x, 512, Wk, 4096, k, 4096, 512, 4096, 512, bk);
    gemm_tiled<<<g1, blk, 0, stream>>>(x, 512, Wv, 4096, v, 4096, 512, 4096, 512, bv);

    // fused scores + alpha-entmax + P*V^T, half token per block
    attn_entmax<<<dim3(1024), blk, 0, stream>>>(q, k, v, res, al);

    dim3 g3(512 / TN, 512 / TM, 8);
    gemm_tiled<<<g3, blk, 0, stream>>>(res, 4096, Wu, 512, part, 512, 512, 512, 512, nullptr);
    reduce_bias<<<dim3(262144 / 256), blk, 0, stream>>>(part, bu, out, 262144, 8);
}

// Round 8
// 416.426 us; speedup vs baseline: 5.9744x; 5.9744x over previous
//
#include <hip/hip_runtime.h>
#include <hip/hip_bf16.h>
#include <stdint.h>

// ---------------------------------------------------------------------------
// bf16 pack/unpack via pure bit ops — no unions, no vector builtins
// (proven functional in round 7; scratch there came from dual x0/x1 arrays).
// ---------------------------------------------------------------------------
__device__ __forceinline__ float blo(uint32_t u) { return __uint_as_float(u << 16); }
__device__ __forceinline__ float bhi(uint32_t u) { return __uint_as_float(u & 0xFFFF0000u); }
__device__ __forceinline__ uint32_t bpack(float lo, float hi) {
    uint32_t ulo = __float_as_uint(lo), uhi = __float_as_uint(hi);
    return ((ulo + 0x8000u) >> 16) | ((uhi + 0x8000u) & 0xFFFF0000u);
}

// ---------------------------------------------------------------------------
// DPP helpers: reductions within each 16-lane row (VALU pipe, no LDS traffic)
// ---------------------------------------------------------------------------
template <int CTRL>
__device__ __forceinline__ float dppmov(float v) {
    return __int_as_float(__builtin_amdgcn_update_dpp(
        0, __float_as_int(v), CTRL, 0xF, 0xF, true));
}
__device__ __forceinline__ float grp_sum16(float v) {
    v += dppmov<0xB1>(v);   // quad_perm xor1
    v += dppmov<0x4E>(v);   // quad_perm xor2
    v += dppmov<0x124>(v);  // row_ror:4
    v += dppmov<0x128>(v);  // row_ror:8
    return v;
}
__device__ __forceinline__ float grp_max16(float v) {
    v = fmaxf(v, dppmov<0xB1>(v));
    v = fmaxf(v, dppmov<0x4E>(v));
    v = fmaxf(v, dppmov<0x124>(v));
    v = fmaxf(v, dppmov<0x128>(v));
    return v;
}

// ---------------------------------------------------------------------------
// Generic fp32 tiled GEMM (unchanged)
// ---------------------------------------------------------------------------
#define TM 64
#define TN 64
#define TK 16

__global__ __launch_bounds__(256) void gemm_tiled(
    const float* __restrict__ A, int lda,
    const float* __restrict__ B, int ldb,
    float* __restrict__ C, int ldc,
    int M, int N, int kc, const float* __restrict__ bias)
{
    __shared__ float As[TK][TM + 4];
    __shared__ float Bs[TK][TN + 4];
    const int tid = threadIdx.x;
    const int bm = blockIdx.y * TM;
    const int bn = blockIdx.x * TN;
    const int k0 = blockIdx.z * kc;
    C += (size_t)blockIdx.z * M * N;

    const int tx = tid & 15;
    const int ty = tid >> 4;

    float acc[4][4];
#pragma unroll
    for (int i = 0; i < 4; ++i)
#pragma unroll
        for (int j = 0; j < 4; ++j)
            acc[i][j] = bias ? bias[bn + tx * 4 + j] : 0.0f;

    const int ar = tid >> 2;
    const int ac = (tid & 3) * 4;
    const int br = tid >> 4;
    const int bc = (tid & 15) * 4;

    for (int kt = k0; kt < k0 + kc; kt += TK) {
        float4 a = *(const float4*)&A[(size_t)(bm + ar) * lda + kt + ac];
        float4 b = *(const float4*)&B[(size_t)(kt + br) * ldb + bn + bc];
        As[ac + 0][ar] = a.x; As[ac + 1][ar] = a.y;
        As[ac + 2][ar] = a.z; As[ac + 3][ar] = a.w;
        *(float4*)&Bs[br][bc] = b;
        __syncthreads();
#pragma unroll
        for (int kk = 0; kk < TK; ++kk) {
            float4 a4 = *(const float4*)&As[kk][ty * 4];
            float4 b4 = *(const float4*)&Bs[kk][tx * 4];
            float av[4] = {a4.x, a4.y, a4.z, a4.w};
            float bv[4] = {b4.x, b4.y, b4.z, b4.w};
#pragma unroll
            for (int i = 0; i < 4; ++i)
#pragma unroll
                for (int j = 0; j < 4; ++j)
                    acc[i][j] = fmaf(av[i], bv[j], acc[i][j]);
        }
        __syncthreads();
    }
#pragma unroll
    for (int i = 0; i < 4; ++i) {
        float4 o = make_float4(acc[i][0], acc[i][1], acc[i][2], acc[i][3]);
        *(float4*)&C[(size_t)(bm + ty * 4 + i) * ldc + bn + tx * 4] = o;
    }
}

// ---------------------------------------------------------------------------
// Fused quarter-token kernel, round 8 = round-6 structure VERBATIM
// (single x[32] per lane, one row per 16-lane group, same pragmas, same
// mean-seeded exact active-set solver) + exactly two changes:
//   1. K/V bf16-packed in LDS (uint4 read = 8 cols; halves LDS instrs+bytes)
//   2. quarter-token blocks (grid 2048), LDS 20 KB -> 6-8 blocks/CU
// Round-4/5/7 lesson: do NOT enlarge per-lane array state; WRITE_SIZE==8MB
// is the no-scratch tripwire.
// ---------------------------------------------------------------------------
#define QROWS 128
#define NSOLVE 4
#define NBISECT 3
#define NNEWTON 6

__global__ __launch_bounds__(256, 4) void attn_entmax(
    const float* qg, const float* kg, const float* vg,
    float* resg, const float* __restrict__ alpha_p)
{
    __shared__ uint32_t ks16[8 * 256];   // [h][j2]: (k[h,2j2], k[h,2j2+1]) bf16
    __shared__ uint32_t vs16[8 * 256];   // [h][j2]: same packing for v
    __shared__ float    qs[8 * QROWS];   // pre-scaled f32 q, this block's rows

    const int t = blockIdx.x >> 2;
    const int base = (blockIdx.x & 3) * QROWS;
    const int tid = threadIdx.x;

    const float alpha = alpha_p[0];
    const float expo = 1.0f / (alpha - 1.0f);      // = 2 for alpha=1.5 (exact)
    const bool fast = (expo == 2.0f);
    const float scl = (alpha - 1.0f) * 0.04419417382415922f;  // (a-1)/sqrt(512)
    const float hispan = powf(1.0f / 512.0f, alpha - 1.0f);   // m - tau_hi

    {   // ---- stage K,V (bf16-packed) and q (f32, pre-scaled by scl)
        const float4* k4 = (const float4*)(kg + (size_t)t * 4096);
        const float4* v4 = (const float4*)(vg + (size_t)t * 4096);
#pragma unroll
        for (int a0 = 0; a0 < 4; ++a0) {
            int idx = tid + 256 * a0;          // h = idx>>7, j4 = idx&127
            int h = idx >> 7, j4 = idx & 127;
            float4 gk = k4[idx];
            float4 gv = v4[idx];
            *(uint2*)&ks16[h * 256 + 2 * j4] =
                make_uint2(bpack(gk.x, gk.y), bpack(gk.z, gk.w));
            *(uint2*)&vs16[h * 256 + 2 * j4] =
                make_uint2(bpack(gv.x, gv.y), bpack(gv.z, gv.w));
        }
        const float4* q4 = (const float4*)(qg + (size_t)t * 4096);
        {
            int h = tid >> 5, i4 = tid & 31;   // 256 float4 = 8h x 32
            float4 g = q4[h * 128 + (base >> 2) + i4];
            g.x *= scl; g.y *= scl; g.z *= scl; g.w *= scl;
            ((float4*)qs)[tid] = g;
        }
    }
    __syncthreads();

    const int lane = tid & 63;
    const int w = tid >> 6;        // wave 0..3
    const int sub = lane >> 4;     // 16-lane group 0..3 (one row each)
    const int lx = lane & 15;

    for (int it = 0; it < QROWS / 16; ++it) {
        const int il = it * 16 + w * 4 + sub;   // local row 0..127

        float qv[8];
#pragma unroll
        for (int h = 0; h < 8; ++h) qv[h] = qs[h * QROWS + il];

        // ---- scores; lane's 32 cols: j = 8*lx + 128*u + e  (e = 0..7)
        float x[32];
        float m = -1e30f, s1a = 0.0f;
#pragma unroll 2
        for (int u = 0; u < 4; ++u) {
            float a0=0,a1=0,a2=0,a3=0,a4=0,a5=0,a6=0,a7=0;
#pragma unroll
            for (int h = 0; h < 8; ++h) {
                uint4 kk = *(const uint4*)&ks16[h * 256 + lx * 4 + 64 * u];
                float qh = qv[h];
                a0 = fmaf(qh, blo(kk.x), a0); a1 = fmaf(qh, bhi(kk.x), a1);
                a2 = fmaf(qh, blo(kk.y), a2); a3 = fmaf(qh, bhi(kk.y), a3);
                a4 = fmaf(qh, blo(kk.z), a4); a5 = fmaf(qh, bhi(kk.z), a5);
                a6 = fmaf(qh, blo(kk.w), a6); a7 = fmaf(qh, bhi(kk.w), a7);
            }
            x[8*u+0]=a0; x[8*u+1]=a1; x[8*u+2]=a2; x[8*u+3]=a3;
            x[8*u+4]=a4; x[8*u+5]=a5; x[8*u+6]=a6; x[8*u+7]=a7;
            m = fmaxf(m, fmaxf(fmaxf(fmaxf(a0,a1),fmaxf(a2,a3)),
                               fmaxf(fmaxf(a4,a5),fmaxf(a6,a7))));
            s1a += ((a0+a1)+(a2+a3)) + ((a4+a5)+(a6+a7));
        }
        m = grp_max16(m);
        const float tlo = m - 1.0f;            // f(tlo) >= 1 always
        const float thi = m - hispan;          // f(thi) <= 1 always

        float tau;
        if (fast) {
            // seed: row mean, clamped into the bracket
            s1a = grp_sum16(s1a);
            tau = fminf(fmaxf(s1a * (1.0f / 512.0f), tlo), thi);
            // exact active-set solves: f is quadratic per support set
#pragma unroll
            for (int itr = 0; itr < NSOLVE; ++itr) {
                float s1 = 0.0f, s2 = 0.0f, nf = 0.0f;
#pragma unroll
                for (int j = 0; j < 32; ++j) {
                    float r = x[j] - tau;
                    float rp = fmaxf(r, 0.0f);
                    s1 += rp;
                    s2 = fmaf(rp, rp, s2);
                    nf += (r > 0.0f) ? 1.0f : 0.0f;
                }
                s1 = grp_sum16(s1);
                s2 = grp_sum16(s2);
                nf = grp_sum16(nf);
                float disc = fmaxf(fmaf(s1, s1, -nf * (s2 - 1.0f)), 0.0f);
                tau += (s1 - sqrtf(disc)) / fmaxf(nf, 1.0f);
                tau = fminf(fmaxf(tau, tlo), thi);
            }
        } else {
            // generic alpha: bisect + Newton (powf path)
            tau = tlo;
            float dm = 1.0f - hispan;
#pragma unroll
            for (int bi = 0; bi < NBISECT; ++bi) {
                dm *= 0.5f;
                float tm = tau + dm;
                float f = 0.0f;
#pragma unroll
                for (int j = 0; j < 32; ++j) {
                    float r = fmaxf(x[j] - tm, 0.0f);
                    f += __powf(r, expo);
                }
                f = grp_sum16(f);
                if (f >= 1.0f) tau = tm;
            }
#pragma unroll
            for (int ni = 0; ni < NNEWTON; ++ni) {
                float f = 0.0f, g = 0.0f;
#pragma unroll
                for (int j = 0; j < 32; ++j) {
                    float r = fmaxf(x[j] - tau, 0.0f);
                    float rp = __powf(r, expo - 1.0f);
                    g += rp; f += rp * r;
                }
                f = grp_sum16(f);
                g = grp_sum16(g);
                tau += (f - 1.0f) / fmaxf(expo * g, 1e-30f);
                tau = fminf(fmaxf(tau, tlo), thi);
            }
        }

        // ---- final (unnormalized) p into x; S for normalization
        float S = 0.0f;
        if (fast) {
#pragma unroll
            for (int j = 0; j < 32; ++j) {
                float r = fmaxf(x[j] - tau, 0.0f);
                x[j] = r * r; S += x[j];
            }
        } else {
#pragma unroll
            for (int j = 0; j < 32; ++j) {
                float r = fmaxf(x[j] - tau, 0.0f);
                x[j] = __powf(r, expo); S += x[j];
            }
        }
        S = grp_sum16(S);
        const float invS = 1.0f / S;

        // ---- res[h,i] = invS * sum_j p[j] * v[h,j]
#pragma unroll
        for (int h = 0; h < 8; ++h) {
            float a = 0.0f;
#pragma unroll 2
            for (int u = 0; u < 4; ++u) {
                uint4 vv = *(const uint4*)&vs16[h * 256 + lx * 4 + 64 * u];
                a = fmaf(x[8*u+0], blo(vv.x), a);
                a = fmaf(x[8*u+1], bhi(vv.x), a);
                a = fmaf(x[8*u+2], blo(vv.y), a);
                a = fmaf(x[8*u+3], bhi(vv.y), a);
                a = fmaf(x[8*u+4], blo(vv.z), a);
                a = fmaf(x[8*u+5], bhi(vv.z), a);
                a = fmaf(x[8*u+6], blo(vv.w), a);
                a = fmaf(x[8*u+7], bhi(vv.w), a);
            }
            a = grp_sum16(a) * invS;
            if (lx == h) resg[(size_t)t * 4096 + h * 512 + base + il] = a;
        }
    }
}

// ---------------------------------------------------------------------------
__global__ __launch_bounds__(256) void reduce_bias(
    const float* __restrict__ part, const float* __restrict__ bu,
    float* __restrict__ out, int MN, int S)
{
    int i = blockIdx.x * 256 + threadIdx.x;
    if (i >= MN) return;
    float a = bu[i & 511];
#pragma unroll
    for (int s = 0; s < 8; ++s) a += part[(size_t)s * MN + i];
    out[i] = a;
}

// ---------------------------------------------------------------------------
extern "C" void kernel_launch(void* const* d_in, const int* in_sizes, int n_in,
                              void* d_out, int out_size, void* d_ws, size_t ws_size,
                              hipStream_t stream)
{
    const float* x  = (const float*)d_in[0];
    const float* Wq = (const float*)d_in[1];
    const float* bq = (const float*)d_in[2];
    const float* Wk = (const float*)d_in[3];
    const float* bk = (const float*)d_in[4];
    const float* Wv = (const float*)d_in[5];
    const float* bv = (const float*)d_in[6];
    const float* Wu = (const float*)d_in[7];
    const float* bu = (const float*)d_in[8];
    const float* al = (const float*)d_in[9];
    float* out = (float*)d_out;
    float* ws = (float*)d_ws;

    // ws layout (floats): q[2M] | k[2M] | v[2M]
    // res aliases q: each attn block reads only its own disjoint q slice
    // (rows base..base+127), then writes exactly that slice — safe without
    // inter-block ordering. Split-K partials alias k (dead after attn).
    float* q = ws;
    float* k = ws + 2097152;
    float* v = ws + 2 * 2097152;
    float* res = q;
    float* part = k;

    dim3 blk(256);

    dim3 g1(4096 / TN, 512 / TM, 1);
    gemm_tiled<<<g1, blk, 0, stream>>>(x, 512, Wq, 4096, q, 4096, 512, 4096, 512, bq);
    gemm_tiled<<<g1, blk, 0, stream>>>(x, 512, Wk, 4096, k, 4096, 512, 4096, 512, bk);
    gemm_tiled<<<g1, blk, 0, stream>>>(x, 512, Wv, 4096, v, 4096, 512, 4096, 512, bv);

    // fused scores + alpha-entmax + P*V^T, quarter token per block
    attn_entmax<<<dim3(2048), blk, 0, stream>>>(q, k, v, res, al);

    dim3 g3(512 / TN, 512 / TM, 8);
    gemm_tiled<<<g3, blk, 0, stream>>>(res, 4096, Wu, 512, part, 512, 512, 512, 512, nullptr);
    reduce_bias<<<dim3(262144 / 256), blk, 0, stream>>>(part, bu, out, 262144, 8);
}

// Round 9
// 415.983 us; speedup vs baseline: 5.9808x; 1.0011x over previous
//
#include <hip/hip_runtime.h>
#include <hip/hip_bf16.h>
#include <stdint.h>

// ---------------------------------------------------------------------------
// bf16 pack/unpack via pure bit ops — no unions, no vector builtins
// (proven functional in round 7; scratch there came from dual x0/x1 arrays).
// ---------------------------------------------------------------------------
__device__ __forceinline__ float blo(uint32_t u) { return __uint_as_float(u << 16); }
__device__ __forceinline__ float bhi(uint32_t u) { return __uint_as_float(u & 0xFFFF0000u); }
__device__ __forceinline__ uint32_t bpack(float lo, float hi) {
    uint32_t ulo = __float_as_uint(lo), uhi = __float_as_uint(hi);
    return ((ulo + 0x8000u) >> 16) | ((uhi + 0x8000u) & 0xFFFF0000u);
}

// ---------------------------------------------------------------------------
// DPP helpers: reductions within each 16-lane row (VALU pipe, no LDS traffic)
// ---------------------------------------------------------------------------
template <int CTRL>
__device__ __forceinline__ float dppmov(float v) {
    return __int_as_float(__builtin_amdgcn_update_dpp(
        0, __float_as_int(v), CTRL, 0xF, 0xF, true));
}
__device__ __forceinline__ float grp_sum16(float v) {
    v += dppmov<0xB1>(v);   // quad_perm xor1
    v += dppmov<0x4E>(v);   // quad_perm xor2
    v += dppmov<0x124>(v);  // row_ror:4
    v += dppmov<0x128>(v);  // row_ror:8
    return v;
}
__device__ __forceinline__ float grp_max16(float v) {
    v = fmaxf(v, dppmov<0xB1>(v));
    v = fmaxf(v, dppmov<0x4E>(v));
    v = fmaxf(v, dppmov<0x124>(v));
    v = fmaxf(v, dppmov<0x128>(v));
    return v;
}

// ---------------------------------------------------------------------------
// Generic fp32 tiled GEMM (unchanged)
// ---------------------------------------------------------------------------
#define TM 64
#define TN 64
#define TK 16

__global__ __launch_bounds__(256) void gemm_tiled(
    const float* __restrict__ A, int lda,
    const float* __restrict__ B, int ldb,
    float* __restrict__ C, int ldc,
    int M, int N, int kc, const float* __restrict__ bias)
{
    __shared__ float As[TK][TM + 4];
    __shared__ float Bs[TK][TN + 4];
    const int tid = threadIdx.x;
    const int bm = blockIdx.y * TM;
    const int bn = blockIdx.x * TN;
    const int k0 = blockIdx.z * kc;
    C += (size_t)blockIdx.z * M * N;

    const int tx = tid & 15;
    const int ty = tid >> 4;

    float acc[4][4];
#pragma unroll
    for (int i = 0; i < 4; ++i)
#pragma unroll
        for (int j = 0; j < 4; ++j)
            acc[i][j] = bias ? bias[bn + tx * 4 + j] : 0.0f;

    const int ar = tid >> 2;
    const int ac = (tid & 3) * 4;
    const int br = tid >> 4;
    const int bc = (tid & 15) * 4;

    for (int kt = k0; kt < k0 + kc; kt += TK) {
        float4 a = *(const float4*)&A[(size_t)(bm + ar) * lda + kt + ac];
        float4 b = *(const float4*)&B[(size_t)(kt + br) * ldb + bn + bc];
        As[ac + 0][ar] = a.x; As[ac + 1][ar] = a.y;
        As[ac + 2][ar] = a.z; As[ac + 3][ar] = a.w;
        *(float4*)&Bs[br][bc] = b;
        __syncthreads();
#pragma unroll
        for (int kk = 0; kk < TK; ++kk) {
            float4 a4 = *(const float4*)&As[kk][ty * 4];
            float4 b4 = *(const float4*)&Bs[kk][tx * 4];
            float av[4] = {a4.x, a4.y, a4.z, a4.w};
            float bv[4] = {b4.x, b4.y, b4.z, b4.w};
#pragma unroll
            for (int i = 0; i < 4; ++i)
#pragma unroll
                for (int j = 0; j < 4; ++j)
                    acc[i][j] = fmaf(av[i], bv[j], acc[i][j]);
        }
        __syncthreads();
    }
#pragma unroll
    for (int i = 0; i < 4; ++i) {
        float4 o = make_float4(acc[i][0], acc[i][1], acc[i][2], acc[i][3]);
        *(float4*)&C[(size_t)(bm + ty * 4 + i) * ldc + bn + tx * 4] = o;
    }
}

// ---------------------------------------------------------------------------
// Fused quarter-token kernel, round 8 = round-6 structure VERBATIM
// (single x[32] per lane, one row per 16-lane group, same pragmas, same
// mean-seeded exact active-set solver) + exactly two changes:
//   1. K/V bf16-packed in LDS (uint4 read = 8 cols; halves LDS instrs+bytes)
//   2. quarter-token blocks (grid 2048), LDS 20 KB -> 6-8 blocks/CU
// Round-4/5/7 lesson: do NOT enlarge per-lane array state; WRITE_SIZE==8MB
// is the no-scratch tripwire.
// ---------------------------------------------------------------------------
#define QROWS 128
#define NSOLVE 4
#define NBISECT 3
#define NNEWTON 6

__global__ __launch_bounds__(256, 4) void attn_entmax(
    const float* qg, const float* kg, const float* vg,
    float* resg, const float* __restrict__ alpha_p)
{
    __shared__ uint32_t ks16[8 * 256];   // [h][j2]: (k[h,2j2], k[h,2j2+1]) bf16
    __shared__ uint32_t vs16[8 * 256];   // [h][j2]: same packing for v
    __shared__ float    qs[8 * QROWS];   // pre-scaled f32 q, this block's rows

    const int t = blockIdx.x >> 2;
    const int base = (blockIdx.x & 3) * QROWS;
    const int tid = threadIdx.x;

    const float alpha = alpha_p[0];
    const float expo = 1.0f / (alpha - 1.0f);      // = 2 for alpha=1.5 (exact)
    const bool fast = (expo == 2.0f);
    const float scl = (alpha - 1.0f) * 0.04419417382415922f;  // (a-1)/sqrt(512)
    const float hispan = powf(1.0f / 512.0f, alpha - 1.0f);   // m - tau_hi

    {   // ---- stage K,V (bf16-packed) and q (f32, pre-scaled by scl)
        const float4* k4 = (const float4*)(kg + (size_t)t * 4096);
        const float4* v4 = (const float4*)(vg + (size_t)t * 4096);
#pragma unroll
        for (int a0 = 0; a0 < 4; ++a0) {
            int idx = tid + 256 * a0;          // h = idx>>7, j4 = idx&127
            int h = idx >> 7, j4 = idx & 127;
            float4 gk = k4[idx];
            float4 gv = v4[idx];
            *(uint2*)&ks16[h * 256 + 2 * j4] =
                make_uint2(bpack(gk.x, gk.y), bpack(gk.z, gk.w));
            *(uint2*)&vs16[h * 256 + 2 * j4] =
                make_uint2(bpack(gv.x, gv.y), bpack(gv.z, gv.w));
        }
        const float4* q4 = (const float4*)(qg + (size_t)t * 4096);
        {
            int h = tid >> 5, i4 = tid & 31;   // 256 float4 = 8h x 32
            float4 g = q4[h * 128 + (base >> 2) + i4];
            g.x *= scl; g.y *= scl; g.z *= scl; g.w *= scl;
            ((float4*)qs)[tid] = g;
        }
    }
    __syncthreads();

    const int lane = tid & 63;
    const int w = tid >> 6;        // wave 0..3
    const int sub = lane >> 4;     // 16-lane group 0..3 (one row each)
    const int lx = lane & 15;

    for (int it = 0; it < QROWS / 16; ++it) {
        const int il = it * 16 + w * 4 + sub;   // local row 0..127

        float qv[8];
#pragma unroll
        for (int h = 0; h < 8; ++h) qv[h] = qs[h * QROWS + il];

        // ---- scores; lane's 32 cols: j = 8*lx + 128*u + e  (e = 0..7)
        float x[32];
        float m = -1e30f, s1a = 0.0f;
#pragma unroll 2
        for (int u = 0; u < 4; ++u) {
            float a0=0,a1=0,a2=0,a3=0,a4=0,a5=0,a6=0,a7=0;
#pragma unroll
            for (int h = 0; h < 8; ++h) {
                uint4 kk = *(const uint4*)&ks16[h * 256 + lx * 4 + 64 * u];
                float qh = qv[h];
                a0 = fmaf(qh, blo(kk.x), a0); a1 = fmaf(qh, bhi(kk.x), a1);
                a2 = fmaf(qh, blo(kk.y), a2); a3 = fmaf(qh, bhi(kk.y), a3);
                a4 = fmaf(qh, blo(kk.z), a4); a5 = fmaf(qh, bhi(kk.z), a5);
                a6 = fmaf(qh, blo(kk.w), a6); a7 = fmaf(qh, bhi(kk.w), a7);
            }
            x[8*u+0]=a0; x[8*u+1]=a1; x[8*u+2]=a2; x[8*u+3]=a3;
            x[8*u+4]=a4; x[8*u+5]=a5; x[8*u+6]=a6; x[8*u+7]=a7;
            m = fmaxf(m, fmaxf(fmaxf(fmaxf(a0,a1),fmaxf(a2,a3)),
                               fmaxf(fmaxf(a4,a5),fmaxf(a6,a7))));
            s1a += ((a0+a1)+(a2+a3)) + ((a4+a5)+(a6+a7));
        }
        m = grp_max16(m);
        const float tlo = m - 1.0f;            // f(tlo) >= 1 always
        const float thi = m - hispan;          // f(thi) <= 1 always

        float tau;
        if (fast) {
            // seed: row mean, clamped into the bracket
            s1a = grp_sum16(s1a);
            tau = fminf(fmaxf(s1a * (1.0f / 512.0f), tlo), thi);
            // exact active-set solves: f is quadratic per support set
#pragma unroll
            for (int itr = 0; itr < NSOLVE; ++itr) {
                float s1 = 0.0f, s2 = 0.0f, nf = 0.0f;
#pragma unroll
                for (int j = 0; j < 32; ++j) {
                    float r = x[j] - tau;
                    float rp = fmaxf(r, 0.0f);
                    s1 += rp;
                    s2 = fmaf(rp, rp, s2);
                    nf += (r > 0.0f) ? 1.0f : 0.0f;
                }
                s1 = grp_sum16(s1);
                s2 = grp_sum16(s2);
                nf = grp_sum16(nf);
                float disc = fmaxf(fmaf(s1, s1, -nf * (s2 - 1.0f)), 0.0f);
                tau += (s1 - sqrtf(disc)) / fmaxf(nf, 1.0f);
                tau = fminf(fmaxf(tau, tlo), thi);
            }
        } else {
            // generic alpha: bisect + Newton (powf path)
            tau = tlo;
            float dm = 1.0f - hispan;
#pragma unroll
            for (int bi = 0; bi < NBISECT; ++bi) {
                dm *= 0.5f;
                float tm = tau + dm;
                float f = 0.0f;
#pragma unroll
                for (int j = 0; j < 32; ++j) {
                    float r = fmaxf(x[j] - tm, 0.0f);
                    f += __powf(r, expo);
                }
                f = grp_sum16(f);
                if (f >= 1.0f) tau = tm;
            }
#pragma unroll
            for (int ni = 0; ni < NNEWTON; ++ni) {
                float f = 0.0f, g = 0.0f;
#pragma unroll
                for (int j = 0; j < 32; ++j) {
                    float r = fmaxf(x[j] - tau, 0.0f);
                    float rp = __powf(r, expo - 1.0f);
                    g += rp; f += rp * r;
                }
                f = grp_sum16(f);
                g = grp_sum16(g);
                tau += (f - 1.0f) / fmaxf(expo * g, 1e-30f);
                tau = fminf(fmaxf(tau, tlo), thi);
            }
        }

        // ---- final (unnormalized) p into x; S for normalization
        float S = 0.0f;
        if (fast) {
#pragma unroll
            for (int j = 0; j < 32; ++j) {
                float r = fmaxf(x[j] - tau, 0.0f);
                x[j] = r * r; S += x[j];
            }
        } else {
#pragma unroll
            for (int j = 0; j < 32; ++j) {
                float r = fmaxf(x[j] - tau, 0.0f);
                x[j] = __powf(r, expo); S += x[j];
            }
        }
        S = grp_sum16(S);
        const float invS = 1.0f / S;

        // ---- res[h,i] = invS * sum_j p[j] * v[h,j]
#pragma unroll
        for (int h = 0; h < 8; ++h) {
            float a = 0.0f;
#pragma unroll 2
            for (int u = 0; u < 4; ++u) {
                uint4 vv = *(const uint4*)&vs16[h * 256 + lx * 4 + 64 * u];
                a = fmaf(x[8*u+0], blo(vv.x), a);
                a = fmaf(x[8*u+1], bhi(vv.x), a);
                a = fmaf(x[8*u+2], blo(vv.y), a);
                a = fmaf(x[8*u+3], bhi(vv.y), a);
                a = fmaf(x[8*u+4], blo(vv.z), a);
                a = fmaf(x[8*u+5], bhi(vv.z), a);
                a = fmaf(x[8*u+6], blo(vv.w), a);
                a = fmaf(x[8*u+7], bhi(vv.w), a);
            }
            a = grp_sum16(a) * invS;
            if (lx == h) resg[(size_t)t * 4096 + h * 512 + base + il] = a;
        }
    }
}

// ---------------------------------------------------------------------------
__global__ __launch_bounds__(256) void reduce_bias(
    const float* __restrict__ part, const float* __restrict__ bu,
    float* __restrict__ out, int MN, int S)
{
    int i = blockIdx.x * 256 + threadIdx.x;
    if (i >= MN) return;
    float a = bu[i & 511];
#pragma unroll
    for (int s = 0; s < 8; ++s) a += part[(size_t)s * MN + i];
    out[i] = a;
}

// ---------------------------------------------------------------------------
extern "C" void kernel_launch(void* const* d_in, const int* in_sizes, int n_in,
                              void* d_out, int out_size, void* d_ws, size_t ws_size,
                              hipStream_t stream)
{
    const float* x  = (const float*)d_in[0];
    const float* Wq = (const float*)d_in[1];
    const float* bq = (const float*)d_in[2];
    const float* Wk = (const float*)d_in[3];
    const float* bk = (const float*)d_in[4];
    const float* Wv = (const float*)d_in[5];
    const float* bv = (const float*)d_in[6];
    const float* Wu = (const float*)d_in[7];
    const float* bu = (const float*)d_in[8];
    const float* al = (const float*)d_in[9];
    float* out = (float*)d_out;
    float* ws = (float*)d_ws;

    // ws layout (floats): q[2M] | k[2M] | v[2M]
    // res aliases q: each attn block reads only its own disjoint q slice
    // (rows base..base+127), then writes exactly that slice — safe without
    // inter-block ordering. Split-K partials alias k (dead after attn).
    float* q = ws;
    float* k = ws + 2097152;
    float* v = ws + 2 * 2097152;
    float* res = q;
    float* part = k;

    dim3 blk(256);

    dim3 g1(4096 / TN, 512 / TM, 1);
    gemm_tiled<<<g1, blk, 0, stream>>>(x, 512, Wq, 4096, q, 4096, 512, 4096, 512, bq);
    gemm_tiled<<<g1, blk, 0, stream>>>(x, 512, Wk, 4096, k, 4096, 512, 4096, 512, bk);
    gemm_tiled<<<g1, blk, 0, stream>>>(x, 512, Wv, 4096, v, 4096, 512, 4096, 512, bv);

    // fused scores + alpha-entmax + P*V^T, quarter token per block
    attn_entmax<<<dim3(2048), blk, 0, stream>>>(q, k, v, res, al);

    dim3 g3(512 / TN, 512 / TM, 8);
    gemm_tiled<<<g3, blk, 0, stream>>>(res, 4096, Wu, 512, part, 512, 512, 512, 512, nullptr);
    reduce_bias<<<dim3(262144 / 256), blk, 0, stream>>>(part, bu, out, 262144, 8);
}